// Round 3
// baseline (110.041 us; speedup 1.0000x reference)
//
#include <hip/hip_runtime.h>

// Sinkhorn top-k, sorted-value domain, x <- 1/(Mx), 200 apps.
// R19 = R18 with the per-app LDS window gather replaced by in-register DPP
// wave shifts. Each lane's 11-dword window w[d] = x_lane(g+d-5) is built from
// the wave's own registers (shr1^k / shl1^k, 0-fill at wave edges, the R16
// primitives); only the 10 boundary lanes per wave (li<5 || li>58) read their
// window from the double-buffered zero-padded LDS array (exec-masked) and
// overwrite the DPP values. All lanes still write x to LDS + 1 barrier/app.
// Dataflow is bit-identical to R18 (DPP interior values == LDS values;
// boundary lanes read pads == global 0-fill), so absmax stays 0.0078125.
// Cuts the per-CU LDS read pipe from ~44 unmasked reads/app to 11 masked
// reads + 4 writes, and hides read latency under the ~40-cyc DPP chain.

#define N      512
#define BATCH  16
#define KTOP   50
#define NAPPS  200
#define NJ     11          // window dwords per row pair
#define COEF   1442.6950408889634f   // log2(e)/EPSILON, EPSILON=1e-3
#define ONEH2  0x3C003C00u
#define NT     256         // threads per block = 4 waves
#define XPAD   5           // zero pad dwords at each end of x buffer
#define XLEN   (NT + 2 * XPAD)

typedef _Float16 h2 __attribute__((ext_vector_type(2)));

static __device__ __forceinline__ h2 pack2(float a, float b) {
    return __builtin_bit_cast(h2, __builtin_amdgcn_cvt_pkrtz(a, b));
}
static __device__ __forceinline__ h2 uh(unsigned v) {
    return __builtin_bit_cast(h2, v);
}
static __device__ __forceinline__ unsigned shr1(unsigned v) {   // lane i <- i-1, 0-fill
    return (unsigned)__builtin_amdgcn_update_dpp(0, (int)v, 0x138, 0xF, 0xF, true);
}
static __device__ __forceinline__ unsigned shl1(unsigned v) {   // lane i <- i+1, 0-fill
    return (unsigned)__builtin_amdgcn_update_dpp(0, (int)v, 0x130, 0xF, 0xF, true);
}

__global__
__attribute__((amdgpu_flat_work_group_size(NT, NT)))
void sinkhorn_topk_kernel(const float* __restrict__ scores,
                          float* __restrict__ out) {
    __shared__ __align__(16) float tv[N];
    __shared__ int                 ti[N];
    __shared__ unsigned            xb[2][XLEN];   // double-buffered x dwords

    const int g  = threadIdx.x;             // 0..255, owns rows 2g, 2g+1
    const int li = g & 63;                  // lane within wave
    const int b  = blockIdx.x;

    ((float2*)tv)[g] = ((const float2*)(scores + b * N))[g];
    ti[2 * g]     = 2 * g;
    ti[2 * g + 1] = 2 * g + 1;
    if (g < XPAD) {                         // zero pads (global 0-fill edges)
        xb[0][g] = 0u;            xb[1][g] = 0u;
        xb[0][XLEN - 1 - g] = 0u; xb[1][XLEN - 1 - g] = 0u;
    }
    xb[0][XPAD + g] = ONEH2;                // x_0 = 1.0 pairs
    __syncthreads();

    // ---- bitonic sort, descending (256 pairs, 1 per thread) ----
    for (int k = 2; k <= N; k <<= 1) {
        for (int j = k >> 1; j > 0; j >>= 1) {
            int i = ((g & ~(j - 1)) << 1) | (g & (j - 1));
            int p = i | j;
            float va = tv[i], vb = tv[p];
            bool up = ((i & k) == 0);
            bool sw = up ? (va < vb) : (va > vb);
            if (sw) {
                tv[i] = vb; tv[p] = va;
                int t_ = ti[i]; ti[i] = ti[p]; ti[p] = t_;
            }
            __syncthreads();
        }
    }

    // ---- K band: both rows of the pair use window dwords 0..10 ----
    const int gb = 2 * g - 10;              // global half-index of window dword 0
    const float t0 = tv[2 * g], t1 = tv[2 * g + 1];
    h2 K2[2][NJ];                           // 22 dwords/lane
#pragma unroll
    for (int d = 0; d < NJ; ++d) {
        int g0 = gb + 2 * d, g1 = g0 + 1;
        int c0 = min(max(g0, 0), N - 1), c1 = min(max(g1, 0), N - 1);
        float s0 = tv[c0], s1 = tv[c1];
        float d00 = t0 - s0, d01 = t0 - s1;
        float d10 = t1 - s0, d11 = t1 - s1;
        K2[0][d] = pack2(exp2f(-COEF * d00 * d00), exp2f(-COEF * d01 * d01));
        K2[1][d] = pack2(exp2f(-COEF * d10 * d10), exp2f(-COEF * d11 * d11));
    }

    // ---- 200 apps: DPP window + masked LDS boundary exchange ----
    const bool isb = (li < 5) || (li > 58); // lanes whose window crosses wave edge
    unsigned w[NJ];
    unsigned x = ONEH2;

    auto run_app = [&](const unsigned* rb, unsigned* wb) {
        // boundary lanes: full window from LDS (issued early, masked)
        unsigned wl[NJ];
        if (isb) {
#pragma unroll
            for (int d = 0; d < NJ; ++d) wl[d] = rb[g + d];   // dwords g-5..g+5
        }
        // interior: window via DPP shifts of the register x (0-fill at edges)
        unsigned r1 = shr1(x), r2 = shr1(r1), r3 = shr1(r2),
                 r4 = shr1(r3), r5 = shr1(r4);
        unsigned l1 = shl1(x), l2 = shl1(l1), l3 = shl1(l2),
                 l4 = shl1(l3), l5 = shl1(l4);
        w[0] = r5; w[1] = r4; w[2] = r3; w[3] = r2; w[4] = r1;
        w[5] = x;
        w[6] = l1; w[7] = l2; w[8] = l3; w[9] = l4; w[10] = l5;
        if (isb) {
#pragma unroll
            for (int d = 0; d < NJ; ++d) w[d] = wl[d];
        }
        // 4 chains (even/odd split per row) for dep-latency cover
        float a0 = __builtin_amdgcn_fdot2(K2[0][0], uh(w[0]), 0.f, false);
        float a1 = __builtin_amdgcn_fdot2(K2[1][0], uh(w[0]), 0.f, false);
        float b0 = __builtin_amdgcn_fdot2(K2[0][1], uh(w[1]), 0.f, false);
        float b1 = __builtin_amdgcn_fdot2(K2[1][1], uh(w[1]), 0.f, false);
#pragma unroll
        for (int d = 2; d < NJ; d += 2) {
            a0 = __builtin_amdgcn_fdot2(K2[0][d], uh(w[d]), a0, false);
            a1 = __builtin_amdgcn_fdot2(K2[1][d], uh(w[d]), a1, false);
            if (d + 1 < NJ) {
                b0 = __builtin_amdgcn_fdot2(K2[0][d + 1], uh(w[d + 1]), b0, false);
                b1 = __builtin_amdgcn_fdot2(K2[1][d + 1], uh(w[d + 1]), b1, false);
            }
        }
        float s0 = a0 + b0, s1 = a1 + b1;
        x = __builtin_bit_cast(unsigned,
                pack2(__builtin_amdgcn_rcpf(s0), __builtin_amdgcn_rcpf(s1)));
        if (wb) {
            wb[XPAD + g] = x;
            __syncthreads();
        }
    };

    unsigned* B0 = &xb[0][0];
    unsigned* B1 = &xb[1][0];
#pragma unroll 1
    for (int it = 0; it < (NAPPS - 2) / 2; ++it) {   // apps 0..197
        run_app(B0, B1);
        run_app(B1, B0);
    }
    run_app(B0, B1);            // app 198
    run_app(B1, nullptr);       // app 199: x final; w = window of app-199 state

    // ---- epilogue: out_row = r_a * sum_{gc<K} K[a][gc] c_gc ----
    unsigned cmask[NJ];
#pragma unroll
    for (int d = 0; d < NJ; ++d) {
        int g0 = gb + 2 * d, g1 = g0 + 1;
        h2 cw = uh(w[d]);
        float c0 = (g0 >= 0 && g0 < KTOP) ? (float)cw[0] : 0.f;
        float c1 = (g1 >= 0 && g1 < KTOP) ? (float)cw[1] : 0.f;
        cmask[d] = __builtin_bit_cast(unsigned, pack2(c0, c1));
    }
    float k0 = 0.f, k1 = 0.f;
#pragma unroll
    for (int d = 0; d < NJ; ++d) {
        k0 = __builtin_amdgcn_fdot2(K2[0][d], uh(cmask[d]), k0, false);
        k1 = __builtin_amdgcn_fdot2(K2[1][d], uh(cmask[d]), k1, false);
    }
    h2 xr = uh(x);
    out[b * N + ti[2 * g]]     = (float)xr[0] * k0;
    out[b * N + ti[2 * g + 1]] = (float)xr[1] * k1;
}

extern "C" void kernel_launch(void* const* d_in, const int* in_sizes, int n_in,
                              void* d_out, int out_size, void* d_ws, size_t ws_size,
                              hipStream_t stream) {
    const float* scores = (const float*)d_in[0];
    float* out = (float*)d_out;
    sinkhorn_topk_kernel<<<dim3(BATCH), dim3(NT), 0, stream>>>(scores, out);
}

// Round 4
// 101.499 us; speedup vs baseline: 1.0842x; 1.0842x over previous
//
#include <hip/hip_runtime.h>

// Sinkhorn top-k, sorted-value domain, x <- 1/(Mx), 200 apps.
// R20: amortize the exchange round-trip (R18's dominant cost, ~300 cyc of
// write-drain + barrier + read latency per app) over EAPP=3 apps using
// overlapped wave domains. 8 waves x 64 lanes; wave w covers dwords
// c = 34w - 15 + li (34 owned + 15 halo/side). Between exchanges, apps run
// fully in-register: window w[d] = x(c+d-5) built by wave-wide DPP shifts
// (0x138/0x130, 0-fill); the correct region shrinks 5 lanes/side per app,
// 3 apps -> exactly the 34 owned lanes. Exchange = masked ds_write of owned
// x + 1 barrier + 1 ds_read_b32 per lane (vs R18's 11 reads + barrier PER
// app). Out-of-range lanes (c<0 || c>=256) are forced x=0 by one v_cndmask
// per app == R18's zero pads; LDS pads [0,15) and [271,302) return 0 at
// refresh for exactly those lanes. Owned-lane dataflow is bit-identical to
// R18 (same K2, window values, 4-chain dot order) -> absmax 0.0078125.
// R19 post-mortem: DPP+branch per-app on TOP of the per-app barrier lost
// 33%; the win requires removing the per-app round-trip, done here.

#define N      512
#define BATCH  16
#define KTOP   50
#define NAPPS  200
#define NJ     11          // window dwords per row pair
#define COEF   1442.6950408889634f   // log2(e)/EPSILON, EPSILON=1e-3
#define ONEH2  0x3C003C00u
#define NT     512         // 8 waves
#define EAPP   3           // apps per exchange
#define OWN    34          // owned dwords per wave = 64 - 2*5*EAPP
#define HALO   15          // 5*EAPP
#define XPAD   15          // LDS pad = HALO
#define XLEN   (8 * OWN + 2 * XPAD)   // 272 + 30 = 302

typedef _Float16 h2 __attribute__((ext_vector_type(2)));

static __device__ __forceinline__ h2 pack2(float a, float b) {
    return __builtin_bit_cast(h2, __builtin_amdgcn_cvt_pkrtz(a, b));
}
static __device__ __forceinline__ h2 uh(unsigned v) {
    return __builtin_bit_cast(h2, v);
}
static __device__ __forceinline__ unsigned shr1(unsigned v) {   // lane i <- i-1, 0-fill (wave_shr1)
    return (unsigned)__builtin_amdgcn_update_dpp(0, (int)v, 0x138, 0xF, 0xF, true);
}
static __device__ __forceinline__ unsigned shl1(unsigned v) {   // lane i <- i+1, 0-fill (wave_shl1)
    return (unsigned)__builtin_amdgcn_update_dpp(0, (int)v, 0x130, 0xF, 0xF, true);
}

__global__
__attribute__((amdgpu_flat_work_group_size(NT, NT)))
void sinkhorn_topk_kernel(const float* __restrict__ scores,
                          float* __restrict__ out) {
    __shared__ __align__(16) float tv[N];
    __shared__ int                 ti[N];
    __shared__ unsigned            xb[2][XLEN];   // double-buffered canonical x
    __shared__ unsigned            dump[64];      // non-owner store sink

    const int g  = threadIdx.x;             // 0..511
    const int li = g & 63;
    const int wv = g >> 6;
    const int b  = blockIdx.x;

    tv[g] = scores[b * N + g];
    ti[g] = g;
    if (g < XLEN) {
        unsigned interior = (g >= XPAD && g < XPAD + 256) ? ONEH2 : 0u;
        xb[0][g] = interior;                // x^0 = 1.0 pairs; pads = 0
        xb[1][g] = 0u;                      // pads = 0 (interior overwritten)
    }
    __syncthreads();

    // ---- bitonic sort, descending (256 pairs; threads < 256 act) ----
    for (int k = 2; k <= N; k <<= 1) {
        for (int j = k >> 1; j > 0; j >>= 1) {
            if (g < 256) {
                int i = ((g & ~(j - 1)) << 1) | (g & (j - 1));
                int p = i | j;
                float va = tv[i], vb = tv[p];
                bool up = ((i & k) == 0);
                bool sw = up ? (va < vb) : (va > vb);
                if (sw) {
                    tv[i] = vb; tv[p] = va;
                    int t_ = ti[i]; ti[i] = ti[p]; ti[p] = t_;
                }
            }
            __syncthreads();
        }
    }

    // ---- K band for this lane's covered dword c ----
    const int  c     = OWN * wv - HALO + li;        // -15 .. 286
    const int  cc    = min(max(c, 0), 255);
    const int  gb    = 2 * c - 10;                  // global half-index of w[0]
    const bool valid = (c >= 0) && (c < 256);
    const bool owner = (li >= HALO) && (li < HALO + OWN) && (c < 256);
    const float t0 = tv[2 * cc], t1 = tv[2 * cc + 1];
    h2 K2[2][NJ];
#pragma unroll
    for (int d = 0; d < NJ; ++d) {
        int g0 = gb + 2 * d, g1 = g0 + 1;
        int c0 = min(max(g0, 0), N - 1), c1 = min(max(g1, 0), N - 1);
        float s0 = tv[c0], s1 = tv[c1];
        float d00 = t0 - s0, d01 = t0 - s1;
        float d10 = t1 - s0, d11 = t1 - s1;
        K2[0][d] = pack2(exp2f(-COEF * d00 * d00), exp2f(-COEF * d01 * d01));
        K2[1][d] = pack2(exp2f(-COEF * d10 * d10), exp2f(-COEF * d11 * d11));
    }

    // ---- app loop: 66 phases x 3 apps + tail of 2 ----
    unsigned w[NJ];
    unsigned x = 0u;

    auto one_app = [&]() {
        unsigned r1 = shr1(x), r2 = shr1(r1), r3 = shr1(r2),
                 r4 = shr1(r3), r5 = shr1(r4);
        unsigned l1 = shl1(x), l2 = shl1(l1), l3 = shl1(l2),
                 l4 = shl1(l3), l5 = shl1(l4);
        w[0] = r5; w[1] = r4; w[2] = r3; w[3] = r2; w[4] = r1;
        w[5] = x;
        w[6] = l1; w[7] = l2; w[8] = l3; w[9] = l4; w[10] = l5;
        float a0 = __builtin_amdgcn_fdot2(K2[0][0], uh(w[0]), 0.f, false);
        float a1 = __builtin_amdgcn_fdot2(K2[1][0], uh(w[0]), 0.f, false);
        float b0 = __builtin_amdgcn_fdot2(K2[0][1], uh(w[1]), 0.f, false);
        float b1 = __builtin_amdgcn_fdot2(K2[1][1], uh(w[1]), 0.f, false);
#pragma unroll
        for (int d = 2; d < NJ; d += 2) {
            a0 = __builtin_amdgcn_fdot2(K2[0][d], uh(w[d]), a0, false);
            a1 = __builtin_amdgcn_fdot2(K2[1][d], uh(w[d]), a1, false);
            if (d + 1 < NJ) {
                b0 = __builtin_amdgcn_fdot2(K2[0][d + 1], uh(w[d + 1]), b0, false);
                b1 = __builtin_amdgcn_fdot2(K2[1][d + 1], uh(w[d + 1]), b1, false);
            }
        }
        float s0 = a0 + b0, s1 = a1 + b1;
        unsigned xn = __builtin_bit_cast(unsigned,
                pack2(__builtin_amdgcn_rcpf(s0), __builtin_amdgcn_rcpf(s1)));
        x = valid ? xn : 0u;                // global zero-pad semantics
    };

#pragma unroll 1
    for (int ph = 0; ph < (NAPPS - 2) / EAPP; ++ph) {   // 66 phases, apps 1..198
        const unsigned* rb = &xb[ph & 1][0];
        unsigned* wb = &xb[(ph & 1) ^ 1][0];
        x = rb[c + XPAD];                   // refresh canonical x (pads give 0)
        one_app(); one_app(); one_app();
        *(owner ? &wb[XPAD + c] : &dump[li]) = x;   // branchless masked store
        __syncthreads();
    }
    // tail: apps 199, 200 read from xb[0] (phase 65 wrote xb[0])
    x = xb[0][c + XPAD];
    one_app();                              // -> x^199 (correct lanes 5..58)
    one_app();                              // -> x^200; w = window of x^199

    // ---- epilogue: out_row = r_a * sum_{gc<K} K[a][gc] c_gc ----
    unsigned cmask[NJ];
#pragma unroll
    for (int d = 0; d < NJ; ++d) {
        int g0 = gb + 2 * d, g1 = g0 + 1;
        h2 cw = uh(w[d]);
        float c0 = (g0 >= 0 && g0 < KTOP) ? (float)cw[0] : 0.f;
        float c1 = (g1 >= 0 && g1 < KTOP) ? (float)cw[1] : 0.f;
        cmask[d] = __builtin_bit_cast(unsigned, pack2(c0, c1));
    }
    float k0 = 0.f, k1 = 0.f;
#pragma unroll
    for (int d = 0; d < NJ; ++d) {
        k0 = __builtin_amdgcn_fdot2(K2[0][d], uh(cmask[d]), k0, false);
        k1 = __builtin_amdgcn_fdot2(K2[1][d], uh(cmask[d]), k1, false);
    }
    if (owner) {
        h2 xr = uh(x);
        out[b * N + ti[2 * c]]     = (float)xr[0] * k0;
        out[b * N + ti[2 * c + 1]] = (float)xr[1] * k1;
    }
}

extern "C" void kernel_launch(void* const* d_in, const int* in_sizes, int n_in,
                              void* d_out, int out_size, void* d_ws, size_t ws_size,
                              hipStream_t stream) {
    const float* scores = (const float*)d_in[0];
    float* out = (float*)d_out;
    sinkhorn_topk_kernel<<<dim3(BATCH), dim3(NT), 0, stream>>>(scores, out);
}